// Round 5
// baseline (1067.376 us; speedup 1.0000x reference)
//
#include <hip/hip_runtime.h>
#include <hip/hip_bf16.h>

#define D 256
#define NEG_SLOPE 0.2f
#define BM 64
#define BN 256
#define BK 64
#define LDK 72   // padded LDS row stride (bf16): 144B = 36 dw == 4 mod 32 banks (2-way = free)
#define SCAN_CHUNK 1024

using bf16x8 = __attribute__((ext_vector_type(8))) __bf16;
using f32x4  = __attribute__((ext_vector_type(4))) float;

__device__ __forceinline__ float bf2f(unsigned short u) {
    return __uint_as_float(((unsigned int)u) << 16);
}
__device__ __forceinline__ unsigned short f2bf(float f) {
    unsigned int u = __float_as_uint(f);
    unsigned int r = (u + 0x7FFF + ((u >> 16) & 1)) >> 16;  // RNE
    return (unsigned short)r;
}
__device__ __forceinline__ unsigned int pack2bf(float a, float b) {
    return (unsigned int)f2bf(a) | ((unsigned int)f2bf(b) << 16);
}

// ---------------- dtype prep ----------------

__global__ __launch_bounds__(256) void conv_bf16_kernel(
    const float* __restrict__ in, unsigned short* __restrict__ out, int n8)
{
    int t = blockIdx.x * blockDim.x + threadIdx.x;
    if (t < n8) {
        const float4 f0 = *(const float4*)(in + (size_t)t * 8);
        const float4 f1 = *(const float4*)(in + (size_t)t * 8 + 4);
        uint4 o;
        o.x = pack2bf(f0.x, f0.y); o.y = pack2bf(f0.z, f0.w);
        o.z = pack2bf(f1.x, f1.y); o.w = pack2bf(f1.z, f1.w);
        *(uint4*)(out + (size_t)t * 8) = o;
    }
}

// WT[n][k] = W[k][n], 256x256, bf16 out; blockIdx.y selects which W
__global__ void transW_kernel(const float* __restrict__ W1, const float* __restrict__ W2,
                              unsigned short* __restrict__ WT1, unsigned short* __restrict__ WT2) {
    const int k = blockIdx.x, n = threadIdx.x;
    const float* W = blockIdx.y ? W2 : W1;
    unsigned short* WT = blockIdx.y ? WT2 : WT1;
    WT[(size_t)n * D + k] = f2bf(W[(size_t)k * D + n]);
}

// ---------------- CSR build ----------------

__global__ void count_kernel(const int* __restrict__ src, int* __restrict__ counts, int E) {
    int t = blockIdx.x * blockDim.x + threadIdx.x;
    if (t < E) atomicAdd(&counts[src[t]], 1);
}

__global__ __launch_bounds__(256) void scan_partial_kernel(
    const int* __restrict__ counts, int* __restrict__ partial, int n)
{
    __shared__ int ws[4];
    const int tid = threadIdx.x;
    const int lane = tid & 63, wv = tid >> 6;
    const int idx = blockIdx.x * SCAN_CHUNK + tid * 4;
    int4 v = make_int4(0, 0, 0, 0);
    if (idx + 3 < n) v = *(const int4*)(counts + idx);
    else {
        if (idx + 0 < n) v.x = counts[idx + 0];
        if (idx + 1 < n) v.y = counts[idx + 1];
        if (idx + 2 < n) v.z = counts[idx + 2];
        if (idx + 3 < n) v.w = counts[idx + 3];
    }
    int s = v.x + v.y + v.z + v.w;
    #pragma unroll
    for (int off = 32; off > 0; off >>= 1) s += __shfl_xor(s, off);
    if (lane == 0) ws[wv] = s;
    __syncthreads();
    if (tid == 0) partial[blockIdx.x] = ws[0] + ws[1] + ws[2] + ws[3];
}

__global__ __launch_bounds__(128) void scan_chunks_kernel(
    const int* __restrict__ partial, int* __restrict__ chunkoff,
    int* __restrict__ row_ptr, int nchunks, int n)
{
    __shared__ int sm[128];
    const int tid = threadIdx.x;
    const int v = (tid < nchunks) ? partial[tid] : 0;
    sm[tid] = v;
    __syncthreads();
    #pragma unroll
    for (int off = 1; off < 128; off <<= 1) {
        int t = (tid >= off) ? sm[tid - off] : 0;
        __syncthreads();
        sm[tid] += t;
        __syncthreads();
    }
    if (tid < nchunks) chunkoff[tid] = sm[tid] - v;
    if (tid == 127) row_ptr[n] = sm[127];
}

__global__ __launch_bounds__(256) void scan_write_kernel(
    const int* __restrict__ counts, const int* __restrict__ chunkoff,
    int* __restrict__ row_ptr, int n)
{
    __shared__ int wsum[4];
    const int tid = threadIdx.x;
    const int lane = tid & 63, wv = tid >> 6;
    const int idx = blockIdx.x * SCAN_CHUNK + tid * 4;
    int4 v = make_int4(0, 0, 0, 0);
    if (idx + 3 < n) v = *(const int4*)(counts + idx);
    else {
        if (idx + 0 < n) v.x = counts[idx + 0];
        if (idx + 1 < n) v.y = counts[idx + 1];
        if (idx + 2 < n) v.z = counts[idx + 2];
        if (idx + 3 < n) v.w = counts[idx + 3];
    }
    const int s = v.x + v.y + v.z + v.w;
    int x = s;
    #pragma unroll
    for (int off = 1; off < 64; off <<= 1) {
        int t = __shfl_up(x, off);
        if (lane >= off) x += t;
    }
    if (lane == 63) wsum[wv] = x;
    __syncthreads();
    int wo = chunkoff[blockIdx.x];
    for (int w = 0; w < 4; ++w) if (w < wv) wo += wsum[w];
    int excl = wo + x - s;
    if (idx + 0 < n) row_ptr[idx + 0] = excl;
    if (idx + 1 < n) row_ptr[idx + 1] = excl + v.x;
    if (idx + 2 < n) row_ptr[idx + 2] = excl + v.x + v.y;
    if (idx + 3 < n) row_ptr[idx + 3] = excl + v.x + v.y + v.z;
}

__global__ void fill_kernel(const int* __restrict__ src, const int* __restrict__ dst,
                            const int* __restrict__ row_ptr, int* __restrict__ fillp,
                            int* __restrict__ col, int E) {
    int t = blockIdx.x * blockDim.x + threadIdx.x;
    if (t < E) {
        int s = src[t];
        int pos = atomicAdd(&fillp[s], 1);
        col[row_ptr[s] + pos] = dst[t];
    }
}

// ---------------- MFMA GEMM: C[M,256](bf16) = A[M,256](bf16) @ WT^T -------
// BM=64, BN=256 (full width): A tile read exactly once. BT[n][k] bf16.

__global__ __launch_bounds__(256) void gemm_mfma(
    const unsigned short* __restrict__ A, const unsigned short* __restrict__ BT,
    unsigned short* __restrict__ C, int M)
{
    __shared__ unsigned short smem[(BM + BN) * LDK];   // 46080 B
    unsigned short* As_ = smem;
    unsigned short* Bs_ = smem + BM * LDK;
    const int tid = threadIdx.x;
    const int m0 = blockIdx.x * BM;
    const int lane = tid & 63;
    const int wv = tid >> 6;
    const int wn = wv * 64;          // wave's 64-col slab
    const int l15 = lane & 15;
    const int quad = lane >> 4;

    f32x4 acc[4][4];
    #pragma unroll
    for (int i = 0; i < 4; ++i)
        #pragma unroll
        for (int j = 0; j < 4; ++j)
            acc[i][j] = (f32x4){0.f, 0.f, 0.f, 0.f};

    for (int k0 = 0; k0 < D; k0 += BK) {
        #pragma unroll
        for (int c = tid; c < BM * 8; c += 256) {       // A: 2 iters
            const int row = c >> 3, b = c & 7;
            const int gr = m0 + row;
            uint4 av = make_uint4(0, 0, 0, 0);
            if (gr < M) av = *(const uint4*)(A + (size_t)gr * D + k0 + b * 8);
            *(uint4*)(As_ + row * LDK + b * 8) = av;
        }
        #pragma unroll
        for (int c = tid; c < BN * 8; c += 256) {       // B: 8 iters (L2-hot, 128KB total)
            const int row = c >> 3, b = c & 7;
            const uint4 bv = *(const uint4*)(BT + (size_t)row * D + k0 + b * 8);
            *(uint4*)(Bs_ + row * LDK + b * 8) = bv;
        }
        __syncthreads();
        #pragma unroll
        for (int s = 0; s < 2; ++s) {
            bf16x8 af[4], bfr[4];
            #pragma unroll
            for (int i = 0; i < 4; ++i)
                af[i] = *(const bf16x8*)(As_ + (i * 16 + l15) * LDK + s * 32 + quad * 8);
            #pragma unroll
            for (int j = 0; j < 4; ++j)
                bfr[j] = *(const bf16x8*)(Bs_ + (wn + j * 16 + l15) * LDK + s * 32 + quad * 8);
            #pragma unroll
            for (int i = 0; i < 4; ++i)
                #pragma unroll
                for (int j = 0; j < 4; ++j)
                    acc[i][j] = __builtin_amdgcn_mfma_f32_16x16x32_bf16(
                        af[i], bfr[j], acc[i][j], 0, 0, 0);
        }
        __syncthreads();
    }

    // epilogue: per-wave 64x72 LDS repack, coalesced stores of wave's col slab
    unsigned short* Cw = smem + wv * (BM * LDK);
    #pragma unroll
    for (int i = 0; i < 4; ++i)
        #pragma unroll
        for (int j = 0; j < 4; ++j)
            #pragma unroll
            for (int r = 0; r < 4; ++r)
                Cw[(i * 16 + quad * 4 + r) * LDK + j * 16 + l15] = f2bf(acc[i][j][r]);
    __syncthreads();
    #pragma unroll
    for (int rr = 0; rr < 64; rr += 2) {
        const int row = rr + (lane >> 5);
        const unsigned int wd = *(const unsigned int*)(Cw + row * LDK + (lane & 31) * 2);
        const int gr = m0 + row;
        if (gr < M)
            *(unsigned int*)(C + (size_t)gr * D + wn + (lane & 31) * 2) = wd;
    }
}

// ---------------- s_src / s_dst ----------------

__global__ __launch_bounds__(256) void score_kernel(
    const unsigned short* __restrict__ h2, const float* __restrict__ a,
    float* __restrict__ s_src, float* __restrict__ s_dst, int Nn)
{
    const int lane = threadIdx.x & 63;
    const int w = threadIdx.x >> 6;
    const int row = blockIdx.x * 4 + w;
    if (row >= Nn) return;
    const ushort4 h = *(const ushort4*)(h2 + (size_t)row * D + lane * 4);
    const float4 a1v = *(const float4*)(a + lane * 4);
    const float4 a2v = *(const float4*)(a + D + lane * 4);
    const float hx = bf2f(h.x), hy = bf2f(h.y), hz = bf2f(h.z), hw = bf2f(h.w);
    float p1 = hx * a1v.x + hy * a1v.y + hz * a1v.z + hw * a1v.w;
    float p2 = hx * a2v.x + hy * a2v.y + hz * a2v.z + hw * a2v.w;
    #pragma unroll
    for (int off = 32; off > 0; off >>= 1) {
        p1 += __shfl_down(p1, off);
        p2 += __shfl_down(p2, off);
    }
    if (lane == 0) { s_src[row] = p1; s_dst[row] = p2; }
}

// ---------------- aggregation: wave per node, 2 rows per load -------------
// lane loads uint4 (8 bf16); 32 lanes cover one row; halves 0/1 of the wave
// process even/odd edges. 4 loads (8 edges) in flight per inner iter.

__global__ __launch_bounds__(256) void agg_kernel(
    const unsigned short* __restrict__ h2, const float* __restrict__ s_src,
    const float* __restrict__ s_dst, const int* __restrict__ row_ptr,
    const int* __restrict__ col, unsigned short* __restrict__ out_bf16,
    float* __restrict__ out_f32, int Nn)
{
    const int lane = threadIdx.x & 63;
    const int node = blockIdx.x * 4 + (threadIdx.x >> 6);
    if (node >= Nn) return;
    const int half = lane >> 5;     // 0: even edges, 1: odd edges
    const int lpos = lane & 31;     // 16B chunk within row
    const int beg = row_ptr[node], end = row_ptr[node + 1];
    const float ssrc = s_src[node];
    const unsigned short* hp = h2 + lpos * 8;
    float acc[8] = {};
    float dpart = 0.f;
    for (int c0 = beg; c0 < end; c0 += 64) {
        const int cnt = min(64, end - c0);
        int j = 0;
        float e = 0.f;
        if (lane < cnt) {
            j = col[c0 + lane];
            const float sc = ssrc + s_dst[j];
            const float l = sc >= 0.f ? sc : NEG_SLOPE * sc;
            e = __expf(-l);
        }
        dpart += e;
        // 8 edges per iter -> 4 independent 1KB row-pair loads in flight.
        // idx <= 63 always (cnt<=64); lanes >= cnt carry e=0,j=0 (harmless).
        for (int k = 0; k < cnt; k += 8) {
            #pragma unroll
            for (int u = 0; u < 4; ++u) {
                const int idx = k + u * 2 + half;
                const int jp = __shfl(j, idx);
                const float ep = __shfl(e, idx);
                const uint4 rw = *(const uint4*)(hp + (size_t)jp * D);
                acc[0] = fmaf(ep, bf2f((unsigned short)(rw.x & 0xFFFF)), acc[0]);
                acc[1] = fmaf(ep, bf2f((unsigned short)(rw.x >> 16)),    acc[1]);
                acc[2] = fmaf(ep, bf2f((unsigned short)(rw.y & 0xFFFF)), acc[2]);
                acc[3] = fmaf(ep, bf2f((unsigned short)(rw.y >> 16)),    acc[3]);
                acc[4] = fmaf(ep, bf2f((unsigned short)(rw.z & 0xFFFF)), acc[4]);
                acc[5] = fmaf(ep, bf2f((unsigned short)(rw.z >> 16)),    acc[5]);
                acc[6] = fmaf(ep, bf2f((unsigned short)(rw.w & 0xFFFF)), acc[6]);
                acc[7] = fmaf(ep, bf2f((unsigned short)(rw.w >> 16)),    acc[7]);
            }
        }
    }
    // merge even/odd halves (lane l <-> l^32 hold same columns)
    #pragma unroll
    for (int t = 0; t < 8; ++t) acc[t] += __shfl_xor(acc[t], 32);
    float denom = dpart;
    #pragma unroll
    for (int off = 32; off > 0; off >>= 1) denom += __shfl_xor(denom, off);
    const float inv = 1.f / denom;
    float v[8];
    #pragma unroll
    for (int t = 0; t < 8; ++t) {
        v[t] = acc[t] * inv;
        v[t] = v[t] > 0.f ? v[t] : expm1f(v[t]);   // elu
    }
    if (half == 0) {
        if (out_bf16) {
            uint4 o;
            o.x = pack2bf(v[0], v[1]); o.y = pack2bf(v[2], v[3]);
            o.z = pack2bf(v[4], v[5]); o.w = pack2bf(v[6], v[7]);
            *(uint4*)(out_bf16 + (size_t)node * D + lpos * 8) = o;
        } else {
            *(float4*)(out_f32 + (size_t)node * D + lpos * 8) =
                make_float4(v[0], v[1], v[2], v[3]);
            *(float4*)(out_f32 + (size_t)node * D + lpos * 8 + 4) =
                make_float4(v[4], v[5], v[6], v[7]);
        }
    }
}

// ---------------- launch ----------------

static inline size_t align_up(size_t x, size_t a) { return (x + a - 1) & ~(a - 1); }

extern "C" void kernel_launch(void* const* d_in, const int* in_sizes, int n_in,
                              void* d_out, int out_size, void* d_ws, size_t ws_size,
                              hipStream_t stream)
{
    const float* emb = (const float*)d_in[0];
    const float* W1  = (const float*)d_in[1];
    const float* a1  = (const float*)d_in[2];
    const float* W2  = (const float*)d_in[3];
    const float* a2  = (const float*)d_in[4];
    const int* edges = (const int*)d_in[5];
    const int Nn = in_sizes[0] / D;
    const int E  = in_sizes[5] / 2;
    const int* src = edges;
    const int* dst = edges + E;
    const int nchunks = (Nn + SCAN_CHUNK - 1) / SCAN_CHUNK;

    size_t off = 0;
    char* base = (char*)d_ws;
    unsigned short* hA = (unsigned short*)(base + off);
    off = align_up(off + (size_t)Nn * D * sizeof(unsigned short), 256);
    unsigned short* hB = (unsigned short*)(base + off);
    off = align_up(off + (size_t)Nn * D * sizeof(unsigned short), 256);
    unsigned short* embb = (unsigned short*)(base + off);
    off = align_up(off + (size_t)Nn * D * sizeof(unsigned short), 256);
    unsigned short* WT1 = (unsigned short*)(base + off);
    off = align_up(off + (size_t)D * D * sizeof(unsigned short), 256);
    unsigned short* WT2 = (unsigned short*)(base + off);
    off = align_up(off + (size_t)D * D * sizeof(unsigned short), 256);
    float* s_src = (float*)(base + off); off = align_up(off + (size_t)Nn * sizeof(float), 256);
    float* s_dst = (float*)(base + off); off = align_up(off + (size_t)Nn * sizeof(float), 256);
    int* row_ptr = (int*)(base + off);   off = align_up(off + (size_t)(Nn + 1) * sizeof(int), 256);
    const size_t cstride = align_up((size_t)Nn * sizeof(int), 256);
    int* counts  = (int*)(base + off);   off += cstride;
    int* fillp   = (int*)(base + off);   off += cstride;   // contiguous with counts
    int* partial = (int*)(base + off);   off = align_up(off + (size_t)nchunks * sizeof(int), 256);
    int* chunkoff= (int*)(base + off);   off = align_up(off + (size_t)nchunks * sizeof(int), 256);
    int* col     = (int*)(base + off);   off = align_up(off + (size_t)E * sizeof(int), 256);

    // prep
    conv_bf16_kernel<<<(Nn * D / 8 + 255) / 256, 256, 0, stream>>>(emb, embb, Nn * D / 8);
    transW_kernel<<<dim3(D, 2), D, 0, stream>>>(W1, W2, WT1, WT2);

    // CSR
    hipMemsetAsync(counts, 0, 2 * cstride, stream);
    count_kernel<<<(E + 255) / 256, 256, 0, stream>>>(src, counts, E);
    scan_partial_kernel<<<nchunks, 256, 0, stream>>>(counts, partial, Nn);
    scan_chunks_kernel<<<1, 128, 0, stream>>>(partial, chunkoff, row_ptr, nchunks, Nn);
    scan_write_kernel<<<nchunks, 256, 0, stream>>>(counts, chunkoff, row_ptr, Nn);
    fill_kernel<<<(E + 255) / 256, 256, 0, stream>>>(src, dst, row_ptr, fillp, col, E);

    const int gblocks = (Nn + BM - 1) / BM;
    // layer 1
    gemm_mfma<<<gblocks, 256, 0, stream>>>(embb, WT1, hA, Nn);
    score_kernel<<<(Nn + 3) / 4, 256, 0, stream>>>(hA, a1, s_src, s_dst, Nn);
    agg_kernel<<<(Nn + 3) / 4, 256, 0, stream>>>(hA, s_src, s_dst, row_ptr, col, hB, nullptr, Nn);
    // layer 2
    gemm_mfma<<<gblocks, 256, 0, stream>>>(hB, WT2, hA, Nn);
    score_kernel<<<(Nn + 3) / 4, 256, 0, stream>>>(hA, a2, s_src, s_dst, Nn);
    agg_kernel<<<(Nn + 3) / 4, 256, 0, stream>>>(hA, s_src, s_dst, row_ptr, col, nullptr,
                                                 (float*)d_out, Nn);
}

// Round 6
// 1047.488 us; speedup vs baseline: 1.0190x; 1.0190x over previous
//
#include <hip/hip_runtime.h>
#include <hip/hip_bf16.h>

#define D 256
#define NEG_SLOPE 0.2f
#define BM 64
#define BN 256
#define BK 64
#define LDK 72   // padded LDS row stride (bf16): 144B = 36 dw == 4 mod 32 banks (2-way = free)
#define SCAN_CHUNK 1024

using bf16x8 = __attribute__((ext_vector_type(8))) __bf16;
using f32x4  = __attribute__((ext_vector_type(4))) float;

__device__ __forceinline__ float bf2f(unsigned short u) {
    return __uint_as_float(((unsigned int)u) << 16);
}
__device__ __forceinline__ unsigned short f2bf(float f) {
    unsigned int u = __float_as_uint(f);
    unsigned int r = (u + 0x7FFF + ((u >> 16) & 1)) >> 16;  // RNE
    return (unsigned short)r;
}
__device__ __forceinline__ unsigned int pack2bf(float a, float b) {
    return (unsigned int)f2bf(a) | ((unsigned int)f2bf(b) << 16);
}

// ---------------- fused prep: conv(emb->bf16) || transpose W1,W2 || count ---
// Independent work split by blockIdx range; overlaps on the device.

__global__ __launch_bounds__(256) void prep_kernel(
    const float* __restrict__ emb, unsigned short* __restrict__ embb, int n8,
    const float* __restrict__ W1, const float* __restrict__ W2,
    unsigned short* __restrict__ WT1, unsigned short* __restrict__ WT2,
    const int* __restrict__ src, int* __restrict__ counts, int E, int nbc)
{
    __shared__ unsigned short Tt[64][65];
    const int bx = blockIdx.x, tid = threadIdx.x;
    if (bx < nbc) {
        // ---- emb fp32 -> bf16, 8 elems/thread
        const int t = bx * 256 + tid;
        if (t < n8) {
            const float4 f0 = *(const float4*)(emb + (size_t)t * 8);
            const float4 f1 = *(const float4*)(emb + (size_t)t * 8 + 4);
            uint4 o;
            o.x = pack2bf(f0.x, f0.y); o.y = pack2bf(f0.z, f0.w);
            o.z = pack2bf(f1.x, f1.y); o.w = pack2bf(f1.z, f1.w);
            *(uint4*)(embb + (size_t)t * 8) = o;
        }
    } else if (bx < nbc + 32) {
        // ---- W transpose via LDS tile: 16 (64x64) tiles per matrix, 2 matrices
        const int tb = bx - nbc;
        const float* W = (tb >> 4) ? W2 : W1;
        unsigned short* WT = (tb >> 4) ? WT2 : WT1;
        const int t16 = tb & 15;
        const int kb = (t16 >> 2) << 6, nb = (t16 & 3) << 6;
        #pragma unroll
        for (int u = 0; u < 16; ++u) {
            const int e = u * 256 + tid;
            const int r = e >> 6, c = e & 63;
            Tt[c][r] = f2bf(W[(size_t)(kb + r) * D + nb + c]);   // coalesced read
        }
        __syncthreads();
        #pragma unroll
        for (int u = 0; u < 16; ++u) {
            const int e = u * 256 + tid;
            const int r = e >> 6, c = e & 63;
            WT[(size_t)(nb + r) * D + kb + c] = Tt[r][c];        // coalesced write
        }
    } else {
        // ---- degree count, 4 edges/thread
        const int cb = bx - nbc - 32;
        #pragma unroll
        for (int u = 0; u < 4; ++u) {
            const int idx = cb * 1024 + u * 256 + tid;
            if (idx < E) atomicAdd(&counts[src[idx]], 1);
        }
    }
}

// ---------------- CSR scan (3-pass, coalesced) ----------------

__global__ __launch_bounds__(256) void scan_partial_kernel(
    const int* __restrict__ counts, int* __restrict__ partial, int n)
{
    __shared__ int ws[4];
    const int tid = threadIdx.x;
    const int lane = tid & 63, wv = tid >> 6;
    const int idx = blockIdx.x * SCAN_CHUNK + tid * 4;
    int4 v = make_int4(0, 0, 0, 0);
    if (idx + 3 < n) v = *(const int4*)(counts + idx);
    else {
        if (idx + 0 < n) v.x = counts[idx + 0];
        if (idx + 1 < n) v.y = counts[idx + 1];
        if (idx + 2 < n) v.z = counts[idx + 2];
        if (idx + 3 < n) v.w = counts[idx + 3];
    }
    int s = v.x + v.y + v.z + v.w;
    #pragma unroll
    for (int off = 32; off > 0; off >>= 1) s += __shfl_xor(s, off);
    if (lane == 0) ws[wv] = s;
    __syncthreads();
    if (tid == 0) partial[blockIdx.x] = ws[0] + ws[1] + ws[2] + ws[3];
}

__global__ __launch_bounds__(128) void scan_chunks_kernel(
    const int* __restrict__ partial, int* __restrict__ chunkoff,
    int* __restrict__ row_ptr, int nchunks, int n)
{
    __shared__ int sm[128];
    const int tid = threadIdx.x;
    const int v = (tid < nchunks) ? partial[tid] : 0;
    sm[tid] = v;
    __syncthreads();
    #pragma unroll
    for (int off = 1; off < 128; off <<= 1) {
        int t = (tid >= off) ? sm[tid - off] : 0;
        __syncthreads();
        sm[tid] += t;
        __syncthreads();
    }
    if (tid < nchunks) chunkoff[tid] = sm[tid] - v;
    if (tid == 127) row_ptr[n] = sm[127];
}

__global__ __launch_bounds__(256) void scan_write_kernel(
    const int* __restrict__ counts, const int* __restrict__ chunkoff,
    int* __restrict__ row_ptr, int n)
{
    __shared__ int wsum[4];
    const int tid = threadIdx.x;
    const int lane = tid & 63, wv = tid >> 6;
    const int idx = blockIdx.x * SCAN_CHUNK + tid * 4;
    int4 v = make_int4(0, 0, 0, 0);
    if (idx + 3 < n) v = *(const int4*)(counts + idx);
    else {
        if (idx + 0 < n) v.x = counts[idx + 0];
        if (idx + 1 < n) v.y = counts[idx + 1];
        if (idx + 2 < n) v.z = counts[idx + 2];
        if (idx + 3 < n) v.w = counts[idx + 3];
    }
    const int s = v.x + v.y + v.z + v.w;
    int x = s;
    #pragma unroll
    for (int off = 1; off < 64; off <<= 1) {
        int t = __shfl_up(x, off);
        if (lane >= off) x += t;
    }
    if (lane == 63) wsum[wv] = x;
    __syncthreads();
    int wo = chunkoff[blockIdx.x];
    for (int w = 0; w < 4; ++w) if (w < wv) wo += wsum[w];
    int excl = wo + x - s;
    if (idx + 0 < n) row_ptr[idx + 0] = excl;
    if (idx + 1 < n) row_ptr[idx + 1] = excl + v.x;
    if (idx + 2 < n) row_ptr[idx + 2] = excl + v.x + v.y;
    if (idx + 3 < n) row_ptr[idx + 3] = excl + v.x + v.y + v.z;
}

__global__ void fill_kernel(const int* __restrict__ src, const int* __restrict__ dst,
                            const int* __restrict__ row_ptr, int* __restrict__ fillp,
                            int* __restrict__ col, int E) {
    int t = blockIdx.x * blockDim.x + threadIdx.x;
    if (t < E) {
        int s = src[t];
        int pos = atomicAdd(&fillp[s], 1);
        col[row_ptr[s] + pos] = dst[t];
    }
}

// ---------------- MFMA GEMM + fused score --------------------------------
// C[M,256](bf16) = A[M,256](bf16) @ WT^T; s_src/s_dst computed from f32 acc
// (block owns full 256-col rows since BN=256 -> no cross-block reduction).

__global__ __launch_bounds__(256) void gemm_mfma(
    const unsigned short* __restrict__ A, const unsigned short* __restrict__ BT,
    const float* __restrict__ av,
    unsigned short* __restrict__ C, float* __restrict__ s_src,
    float* __restrict__ s_dst, int M)
{
    __shared__ unsigned short smem[(BM + BN) * LDK];   // 46080 B
    __shared__ float s_sm[2 * BM];                     // row sums: [src | dst]
    unsigned short* As_ = smem;
    unsigned short* Bs_ = smem + BM * LDK;
    const int tid = threadIdx.x;
    const int m0 = blockIdx.x * BM;
    const int lane = tid & 63;
    const int wv = tid >> 6;
    const int wn = wv * 64;          // wave's 64-col slab
    const int l15 = lane & 15;
    const int quad = lane >> 4;

    if (tid < 2 * BM) s_sm[tid] = 0.f;   // ordered by K-loop's first barrier

    f32x4 acc[4][4];
    #pragma unroll
    for (int i = 0; i < 4; ++i)
        #pragma unroll
        for (int j = 0; j < 4; ++j)
            acc[i][j] = (f32x4){0.f, 0.f, 0.f, 0.f};

    for (int k0 = 0; k0 < D; k0 += BK) {
        // A-tile overrun past M reads adjacent ws buffers (valid memory);
        // contaminated rows are never stored (C/s stores are guarded).
        #pragma unroll
        for (int c = tid; c < BM * 8; c += 256) {
            const int row = c >> 3, b = c & 7;
            const uint4 avv = *(const uint4*)(A + (size_t)(m0 + row) * D + k0 + b * 8);
            *(uint4*)(As_ + row * LDK + b * 8) = avv;
        }
        #pragma unroll
        for (int c = tid; c < BN * 8; c += 256) {
            const int row = c >> 3, b = c & 7;
            const uint4 bv = *(const uint4*)(BT + (size_t)row * D + k0 + b * 8);
            *(uint4*)(Bs_ + row * LDK + b * 8) = bv;
        }
        __syncthreads();
        #pragma unroll
        for (int s = 0; s < 2; ++s) {
            bf16x8 af[4], bfr[4];
            #pragma unroll
            for (int i = 0; i < 4; ++i)
                af[i] = *(const bf16x8*)(As_ + (i * 16 + l15) * LDK + s * 32 + quad * 8);
            #pragma unroll
            for (int j = 0; j < 4; ++j)
                bfr[j] = *(const bf16x8*)(Bs_ + (wn + j * 16 + l15) * LDK + s * 32 + quad * 8);
            #pragma unroll
            for (int i = 0; i < 4; ++i)
                #pragma unroll
                for (int j = 0; j < 4; ++j)
                    acc[i][j] = __builtin_amdgcn_mfma_f32_16x16x32_bf16(
                        af[i], bfr[j], acc[i][j], 0, 0, 0);
        }
        __syncthreads();
    }

    // ---- fused score: per-lane 4-col partials -> shfl over l15 -> LDS add
    {
        float a1v[4], a2v[4];
        #pragma unroll
        for (int j = 0; j < 4; ++j) {
            a1v[j] = av[wn + j * 16 + l15];
            a2v[j] = av[D + wn + j * 16 + l15];
        }
        #pragma unroll
        for (int i = 0; i < 4; ++i)
            #pragma unroll
            for (int r = 0; r < 4; ++r) {
                float ps = 0.f, pd = 0.f;
                #pragma unroll
                for (int j = 0; j < 4; ++j) {
                    ps = fmaf(acc[i][j][r], a1v[j], ps);
                    pd = fmaf(acc[i][j][r], a2v[j], pd);
                }
                #pragma unroll
                for (int off = 1; off < 16; off <<= 1) {
                    ps += __shfl_xor(ps, off);
                    pd += __shfl_xor(pd, off);
                }
                if (l15 == 0) {
                    const int row = i * 16 + quad * 4 + r;
                    atomicAdd(&s_sm[row], ps);
                    atomicAdd(&s_sm[BM + row], pd);
                }
            }
    }

    // ---- epilogue: per-wave LDS repack, coalesced C stores + s stores
    unsigned short* Cw = smem + wv * (BM * LDK);
    #pragma unroll
    for (int i = 0; i < 4; ++i)
        #pragma unroll
        for (int j = 0; j < 4; ++j)
            #pragma unroll
            for (int r = 0; r < 4; ++r)
                Cw[(i * 16 + quad * 4 + r) * LDK + j * 16 + l15] = f2bf(acc[i][j][r]);
    __syncthreads();
    #pragma unroll
    for (int rr = 0; rr < 64; rr += 2) {
        const int row = rr + (lane >> 5);
        const unsigned int wd = *(const unsigned int*)(Cw + row * LDK + (lane & 31) * 2);
        const int gr = m0 + row;
        if (gr < M)
            *(unsigned int*)(C + (size_t)gr * D + wn + (lane & 31) * 2) = wd;
    }
    if (tid < BM) {
        const int gr = m0 + tid;
        if (gr < M) {
            s_src[gr] = s_sm[tid];
            s_dst[gr] = s_sm[BM + tid];
        }
    }
}

// ---------------- aggregation: wave per node (R4 shape), NT final store ---

__global__ __launch_bounds__(256) void agg_kernel(
    const unsigned short* __restrict__ h2, const float* __restrict__ s_src,
    const float* __restrict__ s_dst, const int* __restrict__ row_ptr,
    const int* __restrict__ col, unsigned short* __restrict__ out_bf16,
    float* __restrict__ out_f32, int Nn)
{
    const int lane = threadIdx.x & 63;
    const int node = blockIdx.x * 4 + (threadIdx.x >> 6);
    if (node >= Nn) return;
    const int beg = row_ptr[node], end = row_ptr[node + 1];
    const float ssrc = s_src[node];
    const unsigned short* hp = h2 + lane * 4;   // lane-fixed column base
    float ax = 0.f, ay = 0.f, az = 0.f, aw = 0.f;
    float dpart = 0.f;
    for (int c0 = beg; c0 < end; c0 += 64) {
        const int cnt = min(64, end - c0);
        int j = 0;
        float e = 0.f;
        if (lane < cnt) {
            j = col[c0 + lane];
            const float sc = ssrc + s_dst[j];
            const float l = sc >= 0.f ? sc : NEG_SLOPE * sc;
            e = __expf(-l);
        }
        dpart += e;
        // 4 edges per iter -> 4 independent gathers in flight.
        for (int k = 0; k < cnt; k += 4) {
            const int   j0 = __shfl(j, k),     j1 = __shfl(j, k + 1);
            const int   j2 = __shfl(j, k + 2), j3 = __shfl(j, k + 3);
            const float e0 = __shfl(e, k),     e1 = __shfl(e, k + 1);
            const float e2 = __shfl(e, k + 2), e3 = __shfl(e, k + 3);
            const ushort4 u0 = *(const ushort4*)(hp + (size_t)j0 * D);
            const ushort4 u1 = *(const ushort4*)(hp + (size_t)j1 * D);
            const ushort4 u2 = *(const ushort4*)(hp + (size_t)j2 * D);
            const ushort4 u3 = *(const ushort4*)(hp + (size_t)j3 * D);
            ax = fmaf(e0, bf2f(u0.x), ax); ay = fmaf(e0, bf2f(u0.y), ay);
            az = fmaf(e0, bf2f(u0.z), az); aw = fmaf(e0, bf2f(u0.w), aw);
            ax = fmaf(e1, bf2f(u1.x), ax); ay = fmaf(e1, bf2f(u1.y), ay);
            az = fmaf(e1, bf2f(u1.z), az); aw = fmaf(e1, bf2f(u1.w), aw);
            ax = fmaf(e2, bf2f(u2.x), ax); ay = fmaf(e2, bf2f(u2.y), ay);
            az = fmaf(e2, bf2f(u2.z), az); aw = fmaf(e2, bf2f(u2.w), aw);
            ax = fmaf(e3, bf2f(u3.x), ax); ay = fmaf(e3, bf2f(u3.y), ay);
            az = fmaf(e3, bf2f(u3.z), az); aw = fmaf(e3, bf2f(u3.w), aw);
        }
    }
    float denom = dpart;
    #pragma unroll
    for (int off = 32; off > 0; off >>= 1) denom += __shfl_xor(denom, off);
    const float inv = 1.f / denom;
    float vx = ax * inv, vy = ay * inv, vz = az * inv, vw = aw * inv;
    vx = vx > 0.f ? vx : expm1f(vx);
    vy = vy > 0.f ? vy : expm1f(vy);
    vz = vz > 0.f ? vz : expm1f(vz);
    vw = vw > 0.f ? vw : expm1f(vw);
    if (out_bf16) {
        ushort4 o;
        o.x = f2bf(vx); o.y = f2bf(vy); o.z = f2bf(vz); o.w = f2bf(vw);
        *(ushort4*)(out_bf16 + (size_t)node * D + lane * 4) = o;
    } else {
        // final output: nontemporal (don't churn L2/L3 against the h2 gather)
        f32x4 o = {vx, vy, vz, vw};
        __builtin_nontemporal_store(o, (f32x4*)(out_f32 + (size_t)node * D + lane * 4));
    }
}

// ---------------- launch ----------------

static inline size_t align_up(size_t x, size_t a) { return (x + a - 1) & ~(a - 1); }

extern "C" void kernel_launch(void* const* d_in, const int* in_sizes, int n_in,
                              void* d_out, int out_size, void* d_ws, size_t ws_size,
                              hipStream_t stream)
{
    const float* emb = (const float*)d_in[0];
    const float* W1  = (const float*)d_in[1];
    const float* a1  = (const float*)d_in[2];
    const float* W2  = (const float*)d_in[3];
    const float* a2  = (const float*)d_in[4];
    const int* edges = (const int*)d_in[5];
    const int Nn = in_sizes[0] / D;
    const int E  = in_sizes[5] / 2;
    const int* src = edges;
    const int* dst = edges + E;
    const int nchunks = (Nn + SCAN_CHUNK - 1) / SCAN_CHUNK;
    const int n8 = Nn * D / 8;
    const int nbc = (n8 + 255) / 256;
    const int nbe = (E + 1023) / 1024;

    size_t off = 0;
    char* base = (char*)d_ws;
    unsigned short* hA = (unsigned short*)(base + off);
    off = align_up(off + (size_t)Nn * D * sizeof(unsigned short), 256);
    unsigned short* hB = (unsigned short*)(base + off);
    off = align_up(off + (size_t)Nn * D * sizeof(unsigned short), 256);
    unsigned short* embb = (unsigned short*)(base + off);
    off = align_up(off + (size_t)Nn * D * sizeof(unsigned short), 256);
    unsigned short* WT1 = (unsigned short*)(base + off);
    off = align_up(off + (size_t)D * D * sizeof(unsigned short), 256);
    unsigned short* WT2 = (unsigned short*)(base + off);
    off = align_up(off + (size_t)D * D * sizeof(unsigned short), 256);
    float* s_src = (float*)(base + off); off = align_up(off + (size_t)Nn * sizeof(float), 256);
    float* s_dst = (float*)(base + off); off = align_up(off + (size_t)Nn * sizeof(float), 256);
    int* row_ptr = (int*)(base + off);   off = align_up(off + (size_t)(Nn + 1) * sizeof(int), 256);
    const size_t cstride = align_up((size_t)Nn * sizeof(int), 256);
    int* counts  = (int*)(base + off);   off += cstride;
    int* fillp   = (int*)(base + off);   off += cstride;   // contiguous with counts
    int* partial = (int*)(base + off);   off = align_up(off + (size_t)nchunks * sizeof(int), 256);
    int* chunkoff= (int*)(base + off);   off = align_up(off + (size_t)nchunks * sizeof(int), 256);
    int* col     = (int*)(base + off);   off = align_up(off + (size_t)E * sizeof(int), 256);

    // 1) zero counts+fillp, then fused prep (conv || transW || count)
    hipMemsetAsync(counts, 0, 2 * cstride, stream);
    prep_kernel<<<nbc + 32 + nbe, 256, 0, stream>>>(
        emb, embb, n8, W1, W2, WT1, WT2, src, counts, E, nbc);

    // 2) CSR scan + fill
    scan_partial_kernel<<<nchunks, 256, 0, stream>>>(counts, partial, Nn);
    scan_chunks_kernel<<<1, 128, 0, stream>>>(partial, chunkoff, row_ptr, nchunks, Nn);
    scan_write_kernel<<<nchunks, 256, 0, stream>>>(counts, chunkoff, row_ptr, Nn);
    fill_kernel<<<(E + 255) / 256, 256, 0, stream>>>(src, dst, row_ptr, fillp, col, E);

    const int gblocks = (Nn + BM - 1) / BM;
    // 3) layer 1: gemm (+fused score) -> agg
    gemm_mfma<<<gblocks, 256, 0, stream>>>(embb, WT1, a1, hA, s_src, s_dst, Nn);
    agg_kernel<<<(Nn + 3) / 4, 256, 0, stream>>>(hA, s_src, s_dst, row_ptr, col, hB, nullptr, Nn);
    // 4) layer 2
    gemm_mfma<<<gblocks, 256, 0, stream>>>(hB, WT2, a2, hA, s_src, s_dst, Nn);
    agg_kernel<<<(Nn + 3) / 4, 256, 0, stream>>>(hA, s_src, s_dst, row_ptr, col, nullptr,
                                                 (float*)d_out, Nn);
}